// Round 10
// baseline (1877.021 us; speedup 1.0000x reference)
//
#include <hip/hip_runtime.h>
#include <math.h>

#define BB 16
#define SS 64
#define MM 2048
#define DD 256
#define TOPK 8
#define NCH 16
#define CHR 128            // rows per chunk
#define SCALE 0.0625f      // 1/sqrt(256)

__device__ __forceinline__ float wave_sum(float p) {
    for (int o = 32; o; o >>= 1) p += __shfl_xor(p, o);
    return p;
}

__device__ __forceinline__ void wave_argmax(float& v, int& i) {
    for (int o = 32; o; o >>= 1) {
        float ov = __shfl_xor(v, o);
        int oi = __shfl_xor(i, o);
        if (ov > v || (ov == v && oi < i)) { v = ov; i = oi; }
    }
}

// relaxed agent-scope atomics: bypass non-coherent per-XCD L2 (served at the
// coherence point) without cache-invalidate fences.
__device__ __forceinline__ void astf(float* p, float v) {
    __hip_atomic_store(p, v, __ATOMIC_RELAXED, __HIP_MEMORY_SCOPE_AGENT);
}
__device__ __forceinline__ float aldf(const float* p) {
    return __hip_atomic_load(p, __ATOMIC_RELAXED, __HIP_MEMORY_SCOPE_AGENT);
}
__device__ __forceinline__ void asti(int* p, int v) {
    __hip_atomic_store(p, v, __ATOMIC_RELAXED, __HIP_MEMORY_SCOPE_AGENT);
}
__device__ __forceinline__ int aldi(const int* p) {
    return __hip_atomic_load(p, __ATOMIC_RELAXED, __HIP_MEMORY_SCOPE_AGENT);
}

// generic 32x32-tiled transpose: dst[c][r] = src[r][c]; grid=(C/32, R/32), block=256
__global__ __launch_bounds__(256) void k_tr(const float* __restrict__ src, float* __restrict__ dst,
                                            int sld, int dld) {
    __shared__ float ts[32][33];
    int c0 = blockIdx.x * 32, r0 = blockIdx.y * 32;
    int xx = threadIdx.x & 31, yy = threadIdx.x >> 5;
    for (int i = 0; i < 4; ++i)
        ts[yy + 8 * i][xx] = src[(size_t)(r0 + yy + 8 * i) * sld + c0 + xx];
    __syncthreads();
    for (int i = 0; i < 4; ++i)
        dst[(size_t)(c0 + yy + 8 * i) * dld + r0 + xx] = ts[xx][yy + 8 * i];
}

// C[i][j] = sum_d A[i][d]*B[d][j] (+bias[j]); optional c0o[i] = Arow . bkv. grid = rows
__global__ __launch_bounds__(256) void k_gemv(const float* __restrict__ A, const float* __restrict__ B,
                                              const float* __restrict__ bias, float* __restrict__ C,
                                              const float* __restrict__ bkv, float* __restrict__ c0o) {
    const int i = blockIdx.x, tid = threadIdx.x;
    __shared__ float as[DD];
    as[tid] = A[(size_t)i * DD + tid];
    __syncthreads();
    float a0 = bias ? bias[tid] : 0.f, a1 = 0.f;
#pragma unroll 4
    for (int d = 0; d < DD; d += 2) {
        a0 = fmaf(as[d],     B[(size_t)d * DD + tid],       a0);
        a1 = fmaf(as[d + 1], B[(size_t)(d + 1) * DD + tid], a1);
    }
    C[(size_t)i * DD + tid] = a0 + a1;
    if (c0o && tid < 64) {
        float4 a4 = ((const float4*)as)[tid];
        float4 b4 = ((const float4*)bkv)[tid];
        float p = wave_sum(a4.x * b4.x + a4.y * b4.y + a4.z * b4.z + a4.w * b4.w);
        if (tid == 0) c0o[i] = p;
    }
}

// F[j][d] = sum_k Wu[j][256+k]*Wv[k][d];  cb[j] = sum_k bv[k]*Wu[j][256+k]. grid=256
__global__ __launch_bounds__(256) void k_fuse(const float* __restrict__ Wu, const float* __restrict__ Wv,
                                              const float* __restrict__ bv, float* __restrict__ F,
                                              float* __restrict__ cb) {
    const int j = blockIdx.x, tid = threadIdx.x;
    const float* wuh = Wu + (size_t)j * (2 * DD) + DD;
    float a0 = 0.f, a1 = 0.f;
#pragma unroll 4
    for (int k = 0; k < DD; k += 2) {
        a0 = fmaf(wuh[k],     Wv[(size_t)k * DD + tid],       a0);
        a1 = fmaf(wuh[k + 1], Wv[(size_t)(k + 1) * DD + tid], a1);
    }
    F[(size_t)j * DD + tid] = a0 + a1;
    if (tid < 64) {
        float4 b4 = ((const float4*)bv)[tid];
        float4 w4 = ((const float4*)wuh)[tid];
        float p = wave_sum(b4.x * w4.x + b4.y * w4.y + b4.z * w4.z + b4.w * w4.w);
        if (tid == 0) cb[j] = p;
    }
}

// Sbase[bt][m] = sum_d QK[bt][d] * memT[d][m].  grid=(MM/256, BB*SS/16), block=1024.
__global__ __launch_bounds__(1024) void k_sbase(const float* __restrict__ QK,
                                                const float* __restrict__ memT,
                                                float* __restrict__ Sbase) {
    const int tid = threadIdx.x;
    const int mloc = tid & 255, bs = tid >> 8;       // bs: 0..3
    const int m0 = blockIdx.x * 256, bt0 = blockIdx.y * 16;
    __shared__ float qkS[16][DD];
    for (int i = tid; i < 16 * DD; i += 1024)
        ((float*)qkS)[i] = QK[(size_t)bt0 * DD + i];
    __syncthreads();
    float acc0 = 0.f, acc1 = 0.f, acc2 = 0.f, acc3 = 0.f;
    const float* mp = memT + m0 + mloc;
    const int r0 = bs * 4;
#pragma unroll 4
    for (int d = 0; d < DD; ++d) {
        float v = mp[(size_t)d * MM];
        acc0 = fmaf(qkS[r0][d],     v, acc0);
        acc1 = fmaf(qkS[r0 + 1][d], v, acc1);
        acc2 = fmaf(qkS[r0 + 2][d], v, acc2);
        acc3 = fmaf(qkS[r0 + 3][d], v, acc3);
    }
    size_t ob = (size_t)(bt0 + r0) * MM + m0 + mloc;
    Sbase[ob] = acc0; Sbase[ob + MM] = acc1;
    Sbase[ob + 2 * MM] = acc2; Sbase[ob + 3 * MM] = acc3;
}

__global__ __launch_bounds__(256) void k_zero(int* __restrict__ p, int n) {
    int i = blockIdx.x * 256 + threadIdx.x;
    if (i < n) p[i] = 0;
}

// fence-free barrier: __syncthreads + vmcnt drain (sc stores committed),
// relaxed add + relaxed spin. No cache invalidation -> L2 stays warm.
__device__ __forceinline__ void batch_barrier(unsigned* c, unsigned target) {
    __syncthreads();
    if (threadIdx.x == 0) {
        asm volatile("s_waitcnt vmcnt(0)" ::: "memory");
        __hip_atomic_fetch_add(c, 1u, __ATOMIC_RELAXED, __HIP_MEMORY_SCOPE_AGENT);
        while (__hip_atomic_load(c, __ATOMIC_RELAXED, __HIP_MEMORY_SCOPE_AGENT) < target)
            __builtin_amdgcn_s_sleep(1);
        asm volatile("" ::: "memory");
    }
    __syncthreads();
}

__global__ __launch_bounds__(1024) void k_persist(
    const float* __restrict__ x, const float* __restrict__ memory0,
    const float* __restrict__ Sbase, const float* __restrict__ QK,
    const float* __restrict__ c0All, const float* __restrict__ GXU,
    const float* __restrict__ F, const float* __restrict__ cb,
    const float* __restrict__ Wv, const float* __restrict__ bv,
    float* __restrict__ dval, float* __restrict__ pe2, float* __restrict__ pam2,
    float* __restrict__ candV2, int* __restrict__ candI2,
    int* __restrict__ flagslot, int* __restrict__ listChunk,
    int* __restrict__ chunkCnt, int* __restrict__ slotCnt,
    unsigned* __restrict__ ctr, float* __restrict__ out) {
    // batch-per-XCD swizzle: all 16 chunk-blocks of batch b land on XCD b%8
    const int c = blockIdx.x >> 4, b = blockIdx.x & 15;
    const int tid = threadIdx.x, w = tid >> 6, lane = tid & 63;
    const int col = tid & 255, q = tid >> 8;          // 4 quarters x 256 cols
    __shared__ float qks[DD], xs[DD], amS[DD], gs[DD];
    __shared__ float es[CHR];
    __shared__ float cPart[4][DD];
    __shared__ float peS[16];
    __shared__ int topI[TOPK];
    __shared__ int slotArr[TOPK], wasArr[TOPK];
    unsigned* myctr = ctr + b * 16;     // 64B apart per batch
    unsigned barTarget = 0;

    for (int t = 0; t < SS; ++t) {
        const int bt = (b << 6) + t;
        const int par = t & 1;
        float* peP    = pe2    + (size_t)par * BB * 16;
        float* pamP   = pam2   + (size_t)par * BB * 16 * DD;
        float* candVP = candV2 + (size_t)par * BB * 128;
        int*   candIP = candI2 + (size_t)par * BB * 128;

        if (tid < DD) {
            qks[tid] = QK[(size_t)bt * DD + tid];
            xs[tid]  = x[(size_t)bt * DD + tid];
        }
        const float c0v = c0All[bt];
        const int nd = aldi(&chunkCnt[b * 16 + c]);
        // base scores from precomputed Sbase (512B read replaces old 128KB memT pass)
        if (tid < CHR)
            es[tid] = expf((Sbase[(size_t)bt * MM + c * CHR + tid] + c0v) * SCALE);
        __syncthreads();

        // dirty-row score replacements (wave per dirty row, block-private dval)
        for (int i = w; i < nd; i += 16) {
            int packed = listChunk[(b * 16 + c) * CHR + i];
            int rl = packed & 127, slot = packed >> 7;
            float4 dv = ((const float4*)(dval + ((size_t)b * 512 + slot) * DD))[lane];
            float4 q4 = ((const float4*)qks)[lane];
            float p = wave_sum(dv.x * q4.x + dv.y * q4.y + dv.z * q4.z + dv.w * q4.w);
            if (lane == 0) es[rl] = expf((p + c0v) * SCALE);
        }
        __syncthreads();

        // weighted-mem partial: quarter q does rows q*32..+32, col 'col'
        {
            const float* m0 = memory0 + ((size_t)c * CHR + q * 32) * DD + col;
            const float* eq = es + q * 32;
            float p = 0.f;
#pragma unroll 8
            for (int r = 0; r < 32; ++r) p = fmaf(eq[r], m0[(size_t)r * DD], p);
            for (int i = q; i < nd; i += 4) {
                int packed = listChunk[(b * 16 + c) * CHR + i];
                int rl = packed & 127, slot = packed >> 7;
                float e = es[rl];
                p += e * (dval[((size_t)b * 512 + slot) * DD + col]
                          - memory0[((size_t)c * CHR + rl) * DD + col]);
            }
            cPart[q][col] = p;
        }
        __syncthreads();
        if (tid < DD)                    // combine -> sc store
            astf(&pamP[(size_t)(b * 16 + c) * DD + tid],
                 cPart[0][tid] + cPart[1][tid] + cPart[2][tid] + cPart[3][tid]);
        if (w == 12) {                   // denom partial
            float p = wave_sum(es[lane] + es[lane + 64]);
            if (lane == 0) astf(&peP[b * 16 + c], p);
        } else if (w == 13) {            // chunk-local top-8 candidates
            float v0 = es[lane], v1 = es[lane + 64];
            int i0 = lane, i1 = lane + 64;
            for (int k = 0; k < TOPK; ++k) {
                float bb = v0; int bi = i0;
                if (v1 > v0 || (v1 == v0 && i1 < i0)) { bb = v1; bi = i1; }
                wave_argmax(bb, bi);
                if (lane == 0) {
                    astf(&candVP[b * 128 + c * TOPK + k], bb);
                    asti(&candIP[b * 128 + c * TOPK + k], c * CHR + bi);
                }
                if (i0 == bi) v0 = -1e30f;
                if (i1 == bi) v1 = -1e30f;
            }
        }

        barTarget += 16;
        batch_barrier(myctr, barTarget);             // the ONLY barrier per step

        // am gather (sc loads) + peS
        {
            float a = 0.f;
#pragma unroll
            for (int p2 = q * 4; p2 < q * 4 + 4; ++p2)
                a += aldf(&pamP[(size_t)(b * 16 + p2) * DD + col]);
            cPart[q][col] = a;
        }
        if (tid < 16) peS[tid] = aldf(&peP[b * 16 + tid]);
        __syncthreads();
        if (w >= 4 && w < 8) {           // amS by waves 4-7 (wave 0 merges topI)
            int d = tid - 256;
            float tot = 0.f;
#pragma unroll
            for (int i2 = 0; i2 < 16; ++i2) tot += peS[i2];
            amS[d] = (cPart[0][d] + cPart[1][d] + cPart[2][d] + cPart[3][d]) / tot;
        }
        if (w == 0) {                    // merge 128 candidates -> global top-8 (redundant)
            float v0 = aldf(&candVP[b * 128 + lane]), v1 = aldf(&candVP[b * 128 + 64 + lane]);
            int i0 = aldi(&candIP[b * 128 + lane]), i1 = aldi(&candIP[b * 128 + 64 + lane]);
            for (int k = 0; k < TOPK; ++k) {
                float bb = v0; int bi = i0;
                if (v1 > v0 || (v1 == v0 && i1 < i0)) { bb = v1; bi = i1; }
                wave_argmax(bb, bi);
                if (lane == 0) topI[k] = bi;
                if (i0 == bi) v0 = -1e30f;
                if (i1 == bi) v1 = -1e30f;
            }
        }
        __syncthreads();

        // block-uniform owner test
        bool owner = false;
#pragma unroll
        for (int k = 0; k < TOPK; ++k) owner |= ((topI[k] >> 7) == c);

        if (c == 0) {                    // mem_out -> out (one block per batch)
            float4 a4 = ((const float4*)amS)[lane];
            for (int i = 0; i < 16; ++i) {
                int j = w * 16 + i;
                float4 w4 = ((const float4*)(Wv + (size_t)j * DD))[lane];
                float pv = wave_sum(w4.x * a4.x + w4.y * a4.y + w4.z * a4.z + w4.w * a4.w);
                if (lane == 0) out[(size_t)bt * DD + j] = pv + bv[j];
            }
        }
        if (owner) {                     // full gate vector, only at owner blocks
            float4 a4 = ((const float4*)amS)[lane];
            for (int i = 0; i < 16; ++i) {
                int j = w * 16 + i;
                float4 f4 = ((const float4*)(F + (size_t)j * DD))[lane];
                float pg = wave_sum(f4.x * a4.x + f4.y * a4.y + f4.z * a4.z + f4.w * a4.w);
                if (lane == 0)
                    gs[j] = 1.f / (1.f + expf(-(pg + GXU[(size_t)bt * DD + j] + cb[j])));
            }
            __syncthreads();             // gs ready (block-uniform branch)
            if (w == 0 && lane < TOPK) {
                int row = topI[lane];
                if ((row >> 7) == c) {
                    int fs = flagslot[b * MM + row];
                    int slot, wd = (fs != 0);
                    if (!wd) {
                        slot = atomicAdd(&slotCnt[b], 1);
                        flagslot[b * MM + row] = slot + 1;
                        int cc = atomicAdd(&chunkCnt[b * 16 + c], 1);
                        listChunk[(b * 16 + c) * CHR + cc] = (slot << 7) | (row & 127);
                    } else slot = fs - 1;
                    slotArr[lane] = slot; wasArr[lane] = wd;
                }
            }
            __syncthreads();
            {
                float xv = xs[col], gv = gs[col];
#pragma unroll
                for (int kk = q; kk < TOPK; kk += 4) {
                    int row = topI[kk];
                    if ((row >> 7) == c) {
                        size_t doff = ((size_t)b * 512 + slotArr[kk]) * DD + col;
                        float gathered = wasArr[kk] ? dval[doff]
                                                    : memory0[(size_t)row * DD + col];
                        dval[doff] = (1.f - gv) * gathered + gv * xv;
                    }
                }
            }
        }
        __syncthreads();   // protect shared buffers before next-iter overwrite
    }
}

extern "C" void kernel_launch(void* const* d_in, const int* in_sizes, int n_in,
                              void* d_out, int out_size, void* d_ws, size_t ws_size,
                              hipStream_t stream) {
    const float* x      = (const float*)d_in[0];
    const float* memory = (const float*)d_in[1];
    const float* Wq     = (const float*)d_in[2];
    const float* bq     = (const float*)d_in[3];
    const float* Wk     = (const float*)d_in[4];
    const float* bk     = (const float*)d_in[5];
    const float* Wv     = (const float*)d_in[6];
    const float* bv     = (const float*)d_in[7];
    const float* Wu     = (const float*)d_in[8];
    const float* bu     = (const float*)d_in[9];
    float* out = (float*)d_out;

    float* ws = (float*)d_ws;
    size_t o = 0;
    float* memT  = ws + o; o += (size_t)DD * MM;
    float* WqT   = ws + o; o += DD * DD;
    float* WulT  = ws + o; o += DD * DD;
    float* F     = ws + o; o += DD * DD;
    float* cbv   = ws + o; o += DD;
    float* Q     = ws + o; o += (size_t)BB * SS * DD;
    float* QK    = ws + o; o += (size_t)BB * SS * DD;
    float* GXU   = ws + o; o += (size_t)BB * SS * DD;
    float* c0All = ws + o; o += BB * SS;
    float* Sbase = ws + o; o += (size_t)BB * SS * MM;  // 8 MB
    float* dval  = ws + o; o += (size_t)BB * 512 * DD; // 8 MB
    float* pe2   = ws + o; o += 2 * BB * 16;
    float* pam2  = ws + o; o += (size_t)2 * BB * 16 * DD;
    float* candV2 = ws + o; o += 2 * BB * 128;
    int* candI2    = (int*)(ws + o); o += 2 * BB * 128;
    int* zbase     = (int*)(ws + o);
    int* flagslot  = (int*)(ws + o); o += BB * MM;
    int* listChunk = (int*)(ws + o); o += BB * 16 * CHR;
    int* chunkCnt  = (int*)(ws + o); o += BB * 16;
    int* slotCnt   = (int*)(ws + o); o += BB;
    unsigned* ctr  = (unsigned*)(ws + o); o += BB * 16;
    const int nzero = BB * MM + BB * 16 * CHR + BB * 16 + BB + BB * 16;

    k_tr<<<dim3(DD / 32, MM / 32), 256, 0, stream>>>(memory, memT, DD, MM);
    k_tr<<<dim3(DD / 32, DD / 32), 256, 0, stream>>>(Wq, WqT, DD, DD);
    k_tr<<<dim3(DD / 32, DD / 32), 256, 0, stream>>>(Wu, WulT, 2 * DD, DD);
    k_gemv<<<BB * SS, 256, 0, stream>>>(x, WqT, bq, Q, nullptr, nullptr);
    k_gemv<<<BB * SS, 256, 0, stream>>>(Q, Wk, nullptr, QK, bk, c0All);
    k_gemv<<<BB * SS, 256, 0, stream>>>(x, WulT, bu, GXU, nullptr, nullptr);
    k_fuse<<<DD, 256, 0, stream>>>(Wu, Wv, bv, F, cbv);
    k_sbase<<<dim3(MM / 256, BB * SS / 16), 1024, 0, stream>>>(QK, memT, Sbase);
    k_zero<<<(nzero + 255) / 256, 256, 0, stream>>>(zbase, nzero);
    k_persist<<<BB * NCH, 1024, 0, stream>>>(x, memory, Sbase, QK, c0All, GXU, F, cbv,
                                             Wv, bv, dval, pe2, pam2, candV2, candI2,
                                             flagslot, listChunk, chunkCnt, slotCnt, ctr, out);
}